// Round 1
// baseline (83211.981 us; speedup 1.0000x reference)
//
#include <hip/hip_runtime.h>

#define NWG 256
#define WGS 512

typedef __attribute__((ext_vector_type(4))) float facc4;
typedef __attribute__((ext_vector_type(8))) short bfrag8;

constexpr int B_ = 128, T_ = 512, I_ = 128, H_ = 1024;
constexpr int G_ = 4 * H_;  // 4096

// ---------------- workspace layout (bytes) ----------------
// zeroed region first (memset each launch)
constexpr size_t OFF_BAR  = 0;                                  // barrier struct (256 B)
constexpr size_t OFF_H1F  = 256;                                // 2 x B*H fp32 (ping-pong)
constexpr size_t OFF_H2F  = OFF_H1F + 2ull * B_ * H_ * 4;
constexpr size_t OFF_C1   = OFF_H2F + 2ull * B_ * H_ * 4;
constexpr size_t OFF_C2   = OFF_C1 + (size_t)B_ * H_ * 4;
constexpr size_t OFF_X1F  = OFF_C2 + (size_t)B_ * H_ * 4;       // B*I fp32
constexpr size_t OFF_X2F  = OFF_X1F + (size_t)B_ * I_ * 4;      // B*H fp32
constexpr size_t OFF_H1S  = OFF_X2F + (size_t)B_ * H_ * 4;      // 2 x B*H bf16 shadow
constexpr size_t OFF_H2S  = OFF_H1S + 2ull * B_ * H_ * 2;
constexpr size_t OFF_X1S  = OFF_H2S + 2ull * B_ * H_ * 2;       // B*I bf16
constexpr size_t OFF_X2S  = OFF_X1S + (size_t)B_ * I_ * 2;      // B*H bf16
constexpr size_t OFF_BS1  = OFF_X2S + (size_t)B_ * H_ * 2;      // 4096 fp32 (bih+bhh)
constexpr size_t OFF_BS2  = OFF_BS1 + (size_t)G_ * 4;
constexpr size_t ZERO_BYTES = OFF_BS2 + (size_t)G_ * 4;
// bf16 weights (converted in-kernel each launch)
constexpr size_t OFF_WQ1  = ZERO_BYTES;                         // 3*I*H
constexpr size_t OFF_WR1  = OFF_WQ1 + 3ull * I_ * H_ * 2;       // 2*H*I
constexpr size_t OFF_WIH1 = OFF_WR1 + 2ull * H_ * I_ * 2;       // G*I
constexpr size_t OFF_WHH1 = OFF_WIH1 + (size_t)G_ * I_ * 2;     // G*H
constexpr size_t OFF_WQ2  = OFF_WHH1 + (size_t)G_ * H_ * 2;     // 3*H*H
constexpr size_t OFF_WR2  = OFF_WQ2 + 3ull * H_ * H_ * 2;       // 2*H*H
constexpr size_t OFF_WIH2 = OFF_WR2 + 2ull * H_ * H_ * 2;       // G*H
constexpr size_t OFF_WHH2 = OFF_WIH2 + (size_t)G_ * H_ * 2;     // G*H

struct GBar {
  unsigned leaf[32];
  unsigned root;
  unsigned gen;
};

__device__ __forceinline__ float sigf(float x) { return 1.0f / (1.0f + __expf(-x)); }

__device__ __forceinline__ unsigned short f2bf(float f) {
  union { float f; unsigned u; } v; v.f = f;
  unsigned r = v.u + 0x7FFFu + ((v.u >> 16) & 1u);  // RNE
  return (unsigned short)(r >> 16);
}

// ---- device-wide tree barrier: 32 leaves x 8 WGs, relaxed sc1 atomics + one
// release/acquire fence per WG (thread 0; buffer_wbl2/buffer_inv cover the CU).
__device__ __forceinline__ void gbar(GBar* b) {
  __syncthreads();
  if (threadIdx.x == 0) {
    __builtin_amdgcn_fence(__ATOMIC_RELEASE, "agent");  // flush this XCD's dirty L2
    unsigned g = __hip_atomic_load(&b->gen, __ATOMIC_RELAXED, __HIP_MEMORY_SCOPE_AGENT);
    int leaf = blockIdx.x >> 3;
    unsigned a = __hip_atomic_fetch_add(&b->leaf[leaf], 1u, __ATOMIC_RELAXED,
                                        __HIP_MEMORY_SCOPE_AGENT);
    if (a == 7u) {
      unsigned r = __hip_atomic_fetch_add(&b->root, 1u, __ATOMIC_RELAXED,
                                          __HIP_MEMORY_SCOPE_AGENT);
      if (r == 31u) {
        for (int i = 0; i < 32; i++)
          __hip_atomic_store(&b->leaf[i], 0u, __ATOMIC_RELAXED, __HIP_MEMORY_SCOPE_AGENT);
        __hip_atomic_store(&b->root, 0u, __ATOMIC_RELAXED, __HIP_MEMORY_SCOPE_AGENT);
        __hip_atomic_store(&b->gen, g + 1u, __ATOMIC_RELEASE, __HIP_MEMORY_SCOPE_AGENT);
      }
    }
    while (__hip_atomic_load(&b->gen, __ATOMIC_RELAXED, __HIP_MEMORY_SCOPE_AGENT) == g) {
      __builtin_amdgcn_s_sleep(1);
    }
    __builtin_amdgcn_fence(__ATOMIC_ACQUIRE, "agent");  // invalidate stale L1/L2
  }
  __syncthreads();
}

// ---- one mogrify work unit: 2 16x16 tiles, 8 waves = 2 tiles x 4-way K-split.
// dst[m][n] = 2*sigmoid(A@W^T + bias)[m][n] * src[m][n]   (src may alias dst)
__device__ __forceinline__ void mog_unit(
    const unsigned short* __restrict__ A, int K,       // bf16, B x K row-major
    const unsigned short* __restrict__ W,              // bf16, N x K row-major
    const float* __restrict__ bias,                    // N
    const float* srcF, int srcStride,                  // fp32 src (elementwise)
    float* dstF, unsigned short* dstS,                 // fp32 + bf16 shadow out
    int N, int ntShift, int lu, float (*red)[64][4]) {
  const int tid = threadIdx.x;
  const int lane = tid & 63;
  const int wv = tid >> 6;       // 0..7
  const int slot = wv >> 2;      // tile slot 0/1
  const int role = wv & 3;       // K-split index
  const int tt = lu * 2 + slot;
  const int mt = tt >> ntShift;
  const int nt = tt & ((1 << ntShift) - 1);
  const int l15 = lane & 15, lq = lane >> 4;
  const unsigned short* ap = A + (size_t)(mt * 16 + l15) * K + lq * 8;
  const unsigned short* wp = W + (size_t)(nt * 16 + l15) * K + lq * 8;
  const int kq = K >> 2;
  const int kb = role * kq, ke = kb + kq;
  facc4 acc = {0.f, 0.f, 0.f, 0.f};
  for (int k = kb; k < ke; k += 32) {
    bfrag8 av = *(const bfrag8*)(ap + k);
    bfrag8 bv = *(const bfrag8*)(wp + k);
    acc = __builtin_amdgcn_mfma_f32_16x16x32_bf16(av, bv, acc, 0, 0, 0);
  }
  red[wv][lane][0] = acc[0]; red[wv][lane][1] = acc[1];
  red[wv][lane][2] = acc[2]; red[wv][lane][3] = acc[3];
  __syncthreads();
  if (role == 0) {
    const int n = nt * 16 + l15;
    const float bn = bias[n];
#pragma unroll
    for (int j = 0; j < 4; j++) {
      float d = red[slot * 4 + 0][lane][j] + red[slot * 4 + 1][lane][j] +
                red[slot * 4 + 2][lane][j] + red[slot * 4 + 3][lane][j];
      const int m = mt * 16 + lq * 4 + j;
      float v = 2.0f * sigf(d + bn) * srcF[(size_t)m * srcStride + n];
      dstF[(size_t)m * N + n] = v;
      dstS[(size_t)m * N + n] = f2bf(v);
    }
  }
  __syncthreads();
}

// ---- one LSTM-cell work unit: 2 16x16 tiles over H, 8 waves = 2 tiles x 4 gates.
// gates = x@Wih^T + hm@Whh^T + bsum; c' = sig(f)c + sig(i)tanh(g); h' = sig(o)tanh(c')
__device__ __forceinline__ void cell_unit(
    const unsigned short* __restrict__ X, int Kx,
    const unsigned short* __restrict__ Hm,
    const unsigned short* __restrict__ Wih,
    const unsigned short* __restrict__ Whh,
    const float* __restrict__ bsum,
    float* c, float* hF, unsigned short* hS,
    int lu, float (*red)[64][4]) {
  const int tid = threadIdx.x;
  const int lane = tid & 63;
  const int wv = tid >> 6;
  const int slot = wv >> 2;
  const int gate = wv & 3;       // i,f,g,o
  const int tt = lu * 2 + slot;
  const int mt = tt >> 6;        // H/16 = 64 n-tiles
  const int nt = tt & 63;
  const int l15 = lane & 15, lq = lane >> 4;
  const int wrow = gate * H_ + nt * 16 + l15;
  const unsigned short* xp = X + (size_t)(mt * 16 + l15) * Kx + lq * 8;
  const unsigned short* wi = Wih + (size_t)wrow * Kx + lq * 8;
  const unsigned short* hp = Hm + (size_t)(mt * 16 + l15) * H_ + lq * 8;
  const unsigned short* wh = Whh + (size_t)wrow * H_ + lq * 8;
  facc4 acc = {0.f, 0.f, 0.f, 0.f};
  for (int k = 0; k < Kx; k += 32)
    acc = __builtin_amdgcn_mfma_f32_16x16x32_bf16(*(const bfrag8*)(xp + k),
                                                  *(const bfrag8*)(wi + k), acc, 0, 0, 0);
  for (int k = 0; k < H_; k += 32)
    acc = __builtin_amdgcn_mfma_f32_16x16x32_bf16(*(const bfrag8*)(hp + k),
                                                  *(const bfrag8*)(wh + k), acc, 0, 0, 0);
  red[wv][lane][0] = acc[0]; red[wv][lane][1] = acc[1];
  red[wv][lane][2] = acc[2]; red[wv][lane][3] = acc[3];
  __syncthreads();
  if (gate == 0) {
    const int n = nt * 16 + l15;
    const float bi = bsum[n], bf = bsum[H_ + n], bg = bsum[2 * H_ + n], bo = bsum[3 * H_ + n];
#pragma unroll
    for (int j = 0; j < 4; j++) {
      float iv = sigf(red[slot * 4 + 0][lane][j] + bi);
      float fv = sigf(red[slot * 4 + 1][lane][j] + bf);
      float gv = tanhf(red[slot * 4 + 2][lane][j] + bg);
      float ov = sigf(red[slot * 4 + 3][lane][j] + bo);
      const int m = mt * 16 + lq * 4 + j;
      float cold = c[(size_t)m * H_ + n];
      float cn = fv * cold + iv * gv;
      float hn = ov * tanhf(cn);
      c[(size_t)m * H_ + n] = cn;
      hF[(size_t)m * H_ + n] = hn;
      hS[(size_t)m * H_ + n] = f2bf(hn);
    }
  }
  __syncthreads();
}

__global__ __launch_bounds__(WGS, 2) void moglstm_kernel(
    const float* __restrict__ in_seq,
    const float* __restrict__ c1Q, const float* __restrict__ c1Qb,
    const float* __restrict__ c1R, const float* __restrict__ c1Rb,
    const float* __restrict__ c1Wih, const float* __restrict__ c1Whh,
    const float* __restrict__ c1bih, const float* __restrict__ c1bhh,
    const float* __restrict__ c2Q, const float* __restrict__ c2Qb,
    const float* __restrict__ c2R, const float* __restrict__ c2Rb,
    const float* __restrict__ c2Wih, const float* __restrict__ c2Whh,
    const float* __restrict__ c2bih, const float* __restrict__ c2bhh,
    const float* __restrict__ linW, const float* __restrict__ linb,
    char* ws, float* __restrict__ out) {
  __shared__ float red[8][64][4];

  GBar* bar = (GBar*)(ws + OFF_BAR);
  float* h1f0 = (float*)(ws + OFF_H1F);
  float* h1f1 = h1f0 + (size_t)B_ * H_;
  float* h2f0 = (float*)(ws + OFF_H2F);
  float* h2f1 = h2f0 + (size_t)B_ * H_;
  float* c1f = (float*)(ws + OFF_C1);
  float* c2f = (float*)(ws + OFF_C2);
  float* x1f = (float*)(ws + OFF_X1F);
  float* x2f = (float*)(ws + OFF_X2F);
  unsigned short* h1s0 = (unsigned short*)(ws + OFF_H1S);
  unsigned short* h1s1 = h1s0 + (size_t)B_ * H_;
  unsigned short* h2s0 = (unsigned short*)(ws + OFF_H2S);
  unsigned short* h2s1 = h2s0 + (size_t)B_ * H_;
  unsigned short* x1s = (unsigned short*)(ws + OFF_X1S);
  unsigned short* x2s = (unsigned short*)(ws + OFF_X2S);
  float* bs1 = (float*)(ws + OFF_BS1);
  float* bs2 = (float*)(ws + OFF_BS2);
  unsigned short* wq1 = (unsigned short*)(ws + OFF_WQ1);
  unsigned short* wr1 = (unsigned short*)(ws + OFF_WR1);
  unsigned short* wih1 = (unsigned short*)(ws + OFF_WIH1);
  unsigned short* whh1 = (unsigned short*)(ws + OFF_WHH1);
  unsigned short* wq2 = (unsigned short*)(ws + OFF_WQ2);
  unsigned short* wr2 = (unsigned short*)(ws + OFF_WR2);
  unsigned short* wih2 = (unsigned short*)(ws + OFF_WIH2);
  unsigned short* whh2 = (unsigned short*)(ws + OFF_WHH2);

  // ---- init: fp32 -> bf16 weight conversion + bias sums (grid-strided)
  {
    size_t gt = (size_t)blockIdx.x * WGS + threadIdx.x;
    const size_t gs = (size_t)NWG * WGS;
    const float* srcs[8] = {c1Q, c1R, c1Wih, c1Whh, c2Q, c2R, c2Wih, c2Whh};
    unsigned short* dsts[8] = {wq1, wr1, wih1, whh1, wq2, wr2, wih2, whh2};
    const size_t cnts[8] = {3ull * I_ * H_, 2ull * H_ * I_, (size_t)G_ * I_,
                            (size_t)G_ * H_, 3ull * H_ * H_, 2ull * H_ * H_,
                            (size_t)G_ * H_, (size_t)G_ * H_};
    for (int a = 0; a < 8; a++)
      for (size_t i = gt; i < cnts[a]; i += gs) dsts[a][i] = f2bf(srcs[a][i]);
    for (size_t i = gt; i < (size_t)G_; i += gs) bs1[i] = c1bih[i] + c1bhh[i];
    for (size_t i = gt; i < (size_t)G_; i += gs) bs2[i] = c2bih[i] + c2bhh[i];
  }
  gbar(bar);

  const int wg = blockIdx.x;
  // phase p runs layer-1 step t=p and layer-2 step t=p-1 concurrently
  for (int p = 0; p <= T_; ++p) {
    const int q = p & 1;    // layer-1 state parity
    const int q2 = 1 - q;   // layer-2 state parity ((p-1)&1)
    const bool doL1 = (p < T_);
    const bool doL2 = (p > 0);
    float* h1q = q ? h1f1 : h1f0;
    float* h1o = q ? h1f0 : h1f1;
    unsigned short* h1sq = q ? h1s1 : h1s0;
    unsigned short* h1so = q ? h1s0 : h1s1;
    float* h2q2 = q2 ? h2f1 : h2f0;
    float* h2o = q ? h2f1 : h2f0;     // L2 cell writes parity q
    unsigned short* h2sq2 = q2 ? h2s1 : h2s0;
    unsigned short* h2so = q ? h2s1 : h2s0;

    for (int s = 0; s < 6; ++s) {
      const int u2 = doL2 ? 256 : 0;
      const int u1 = doL1 ? ((s == 1 || s == 3 || s == 5) ? 256 : 32) : 0;
      for (int u = wg; u < u2 + u1; u += NWG) {
        if (u < u2) {
          const int lu = u;  // layer 2, step p-1
          switch (s) {
            case 0: mog_unit(h2sq2, H_, wq2, c2Qb, h1q, H_, x2f, x2s, H_, 6, lu, red); break;
            case 1: mog_unit(x2s, H_, wr2, c2Rb, h2q2, H_, h2q2, h2sq2, H_, 6, lu, red); break;
            case 2: mog_unit(h2sq2, H_, wq2 + 1ull * H_ * H_, c2Qb + H_, x2f, H_, x2f, x2s, H_, 6, lu, red); break;
            case 3: mog_unit(x2s, H_, wr2 + 1ull * H_ * H_, c2Rb + H_, h2q2, H_, h2q2, h2sq2, H_, 6, lu, red); break;
            case 4: mog_unit(h2sq2, H_, wq2 + 2ull * H_ * H_, c2Qb + 2 * H_, x2f, H_, x2f, x2s, H_, 6, lu, red); break;
            case 5: cell_unit(x2s, H_, h2sq2, wih2, whh2, bs2, c2f, h2o, h2so, lu, red); break;
          }
        } else {
          const int lu = u - u2;  // layer 1, step p
          switch (s) {
            case 0: mog_unit(h1sq, H_, wq1, c1Qb, in_seq + (size_t)p * I_, T_ * I_, x1f, x1s, I_, 3, lu, red); break;
            case 1: mog_unit(x1s, I_, wr1, c1Rb, h1q, H_, h1q, h1sq, H_, 6, lu, red); break;
            case 2: mog_unit(h1sq, H_, wq1 + 1ull * I_ * H_, c1Qb + I_, x1f, I_, x1f, x1s, I_, 3, lu, red); break;
            case 3: mog_unit(x1s, I_, wr1 + 1ull * H_ * I_, c1Rb + H_, h1q, H_, h1q, h1sq, H_, 6, lu, red); break;
            case 4: mog_unit(h1sq, H_, wq1 + 2ull * I_ * H_, c1Qb + 2 * I_, x1f, I_, x1f, x1s, I_, 3, lu, red); break;
            case 5: cell_unit(x1s, I_, h1sq, wih1, whh1, bs1, c1f, h1o, h1so, lu, red); break;
          }
        }
      }
      gbar(bar);
    }
  }

  // ---- final linear: out[b] = dot(h2_final[b,:], linW) + linb; h2_final = parity 0
  if (wg == 0) {
    float* rf = (float*)red;
    const int tid = threadIdx.x;
    const int b = tid >> 2, qq = tid & 3;
    const float* row = h2f0 + (size_t)b * H_ + qq * 256;
    const float* w = linW + qq * 256;
    float s = 0.f;
    for (int k = 0; k < 256; k++) s += row[k] * w[k];
    rf[tid] = s;
    __syncthreads();
    if (tid < B_)
      out[tid] = rf[tid * 4] + rf[tid * 4 + 1] + rf[tid * 4 + 2] + rf[tid * 4 + 3] + linb[0];
  }
}

extern "C" void kernel_launch(void* const* d_in, const int* in_sizes, int n_in,
                              void* d_out, int out_size, void* d_ws, size_t ws_size,
                              hipStream_t stream) {
  const float* in_seq = (const float*)d_in[0];
  const float* c1Q = (const float*)d_in[1];
  const float* c1Qb = (const float*)d_in[2];
  const float* c1R = (const float*)d_in[3];
  const float* c1Rb = (const float*)d_in[4];
  const float* c1Wih = (const float*)d_in[5];
  const float* c1Whh = (const float*)d_in[6];
  const float* c1bih = (const float*)d_in[7];
  const float* c1bhh = (const float*)d_in[8];
  const float* c2Q = (const float*)d_in[9];
  const float* c2Qb = (const float*)d_in[10];
  const float* c2R = (const float*)d_in[11];
  const float* c2Rb = (const float*)d_in[12];
  const float* c2Wih = (const float*)d_in[13];
  const float* c2Whh = (const float*)d_in[14];
  const float* c2bih = (const float*)d_in[15];
  const float* c2bhh = (const float*)d_in[16];
  const float* linW = (const float*)d_in[17];
  const float* linb = (const float*)d_in[18];

  // zero states, shadows, bias sums, barrier (weights are re-converted in-kernel)
  hipMemsetAsync(d_ws, 0, ZERO_BYTES, stream);
  moglstm_kernel<<<dim3(NWG), dim3(WGS), 0, stream>>>(
      in_seq, c1Q, c1Qb, c1R, c1Rb, c1Wih, c1Whh, c1bih, c1bhh,
      c2Q, c2Qb, c2R, c2Rb, c2Wih, c2Whh, c2bih, c2bhh,
      linW, linb, (char*)d_ws, (float*)d_out);
}